// Round 3
// baseline (253.303 us; speedup 1.0000x reference)
//
#include <hip/hip_runtime.h>
#include <hip/hip_bf16.h>
#include <stdint.h>

#define TB 2
#define TS 2048
#define TD 1024
#define TH 16
#define THS 64
#define TK 1024  // inner dim of both GEMMs

typedef __attribute__((ext_vector_type(8))) short short8;
typedef __attribute__((ext_vector_type(4))) short short4v;
typedef __attribute__((ext_vector_type(4))) float f32x4;
typedef __attribute__((ext_vector_type(16))) float f32x16;
typedef __attribute__((ext_vector_type(4))) unsigned int uint4v;

static __device__ __forceinline__ unsigned short f2bf(float f) {
  union { float f; unsigned u; } v; v.f = f;
  unsigned r = v.u + 0x7FFFu + ((v.u >> 16) & 1u);  // RTNE
  return (unsigned short)(r >> 16);
}

// pack two f32 -> (hi:bf16(b), lo:bf16(a))
static __device__ __forceinline__ unsigned cvtpk(float a, float b) {
  unsigned r;
  asm("v_cvt_pk_bf16_f32 %0, %1, %2" : "=v"(r) : "v"(a), "v"(b));
  return r;
}

// exchange: a.lanes[32:63] <-> b.lanes[0:31]
static __device__ __forceinline__ void swap32(unsigned& a, unsigned& b) {
  asm("v_permlane32_swap_b32 %0, %1" : "+v"(a), "+v"(b));
}

static __device__ __forceinline__ void async_copy16(const void* g, void* l) {
  __builtin_amdgcn_global_load_lds(
      (const __attribute__((address_space(1))) unsigned int*)g,
      (__attribute__((address_space(3))) unsigned int*)l, 16, 0, 0);
}

// ---------------- elementwise fp32 -> bf16 cast ----------------
__global__ __launch_bounds__(256) void k_cvt_bf16x4(const float* __restrict__ in,
                                                    ushort4* __restrict__ out, int n4) {
  int i = blockIdx.x * blockDim.x + threadIdx.x;
  if (i >= n4) return;
  float4 v = ((const float4*)in)[i];
  out[i] = make_ushort4(f2bf(v.x), f2bf(v.y), f2bf(v.z), f2bf(v.w));
}

// ---------------- fp32 [R][C] -> bf16 [C][R] transpose ----------------
__global__ __launch_bounds__(256) void k_transpose_bf(const float* __restrict__ in,
                                                      unsigned short* __restrict__ out,
                                                      int R, int C) {
  __shared__ float tile[32][33];
  const int tx = threadIdx.x & 31, ty = threadIdx.x >> 5;  // ty 0..7
  const int r0 = blockIdx.y * 32, c0 = blockIdx.x * 32;
#pragma unroll
  for (int i = 0; i < 32; i += 8)
    tile[ty + i][tx] = in[(size_t)(r0 + ty + i) * C + c0 + tx];
  __syncthreads();
#pragma unroll
  for (int i = 0; i < 32; i += 8)
    out[(size_t)(c0 + ty + i) * R + r0 + tx] = f2bf(tile[tx][ty + i]);
}

// ---------------- shared GEMM core: C[128x128] tile, K=1024, A[M][K] bf16, BT[N][K] bf16 ----------------
__device__ __forceinline__ void gemm_core_k1024(const unsigned short* __restrict__ A,
                                                const unsigned short* __restrict__ BT,
                                                int m0, int n0,
                                                unsigned short* sA, unsigned short* sB,
                                                f32x4 acc[4][4]) {
  const int tid = threadIdx.x;
  const int wave = tid >> 6, lane = tid & 63;
  const int wm = wave >> 1, wn = wave & 1;

  const unsigned short* gsrc = (wave < 2) ? A : BT;
  const int row0 = (wave < 2) ? m0 : n0;
  unsigned short* lbase = (wave < 2) ? sA : sB;
  const int cw = (wave & 1) * 4;
  const size_t gr = (size_t)(row0 + cw * 16 + (lane >> 2)) * TK + (lane & 3) * 8;

#pragma unroll
  for (int mi = 0; mi < 4; ++mi)
#pragma unroll
    for (int ni = 0; ni < 4; ++ni)
      acc[mi][ni] = (f32x4){0.f, 0.f, 0.f, 0.f};

  auto stage = [&](int buf, int kt) {
    const unsigned short* g = gsrc + gr + kt * 32;
    unsigned short* l = lbase + buf * 4096 + cw * 512;
#pragma unroll
    for (int c = 0; c < 4; ++c)
      async_copy16(g + (size_t)c * 16 * TK, l + c * 512);
  };

  stage(0, 0);
  __syncthreads();

  const int l15 = lane & 15, lk8 = (lane >> 4) * 8;
  const int aoff = (wm * 64 + l15) * 32 + lk8;
  const int boff = (wn * 64 + l15) * 32 + lk8;

  for (int kt = 0; kt < TK / 32; ++kt) {
    const int buf = kt & 1;
    if (kt + 1 < TK / 32) stage(buf ^ 1, kt + 1);
    short8 af[4], bfr[4];
#pragma unroll
    for (int i = 0; i < 4; ++i) {
      af[i] = *(const short8*)&sA[buf * 4096 + aoff + i * 16 * 32];
      bfr[i] = *(const short8*)&sB[buf * 4096 + boff + i * 16 * 32];
    }
#pragma unroll
    for (int mi = 0; mi < 4; ++mi)
#pragma unroll
      for (int ni = 0; ni < 4; ++ni)
        acc[mi][ni] = __builtin_amdgcn_mfma_f32_16x16x32_bf16(af[mi], bfr[ni], acc[mi][ni], 0, 0, 0);
    __syncthreads();
  }
}

// ---------------- GEMM1: qkv = xb @ waT^T + bias, scatter to Q/K [B,H,S,HS] and VT [B,H,HS,S] ----------------
__global__ __launch_bounds__(256) void k_gemm_qkv(const unsigned short* __restrict__ A,
                                                  const unsigned short* __restrict__ BT,
                                                  const float* __restrict__ bias,
                                                  unsigned short* __restrict__ Qo,
                                                  unsigned short* __restrict__ Ko,
                                                  unsigned short* __restrict__ VTo) {
  __shared__ unsigned short sA[2 * 4096];
  __shared__ unsigned short sB[2 * 4096];
  f32x4 acc[4][4];
  const int m0 = blockIdx.y * 128, n0 = blockIdx.x * 128;
  gemm_core_k1024(A, BT, m0, n0, sA, sB, acc);

  const int lane = threadIdx.x & 63, wave = threadIdx.x >> 6;
  const int wm = wave >> 1, wn = wave & 1;
  const int lr4 = (lane >> 4) * 4, l15 = lane & 15;
#pragma unroll
  for (int mi = 0; mi < 4; ++mi) {
    const int row = m0 + wm * 64 + mi * 16 + lr4;
#pragma unroll
    for (int ni = 0; ni < 4; ++ni) {
      const int col = n0 + wn * 64 + ni * 16 + l15;
      const float bi = bias[col];
      const int reg = col >> 10;      // 0:q 1:k 2:v
      const int d1 = col & 1023;
      const int h = d1 >> 6, d = d1 & 63;
#pragma unroll
      for (int j = 0; j < 4; ++j) {
        const int t = row + j;
        const int b = t >> 11, s = t & 2047;
        const unsigned short bv = f2bf(acc[mi][ni][j] + bi);
        if (reg == 0)
          Qo[(((size_t)b * TH + h) * TS + s) * THS + d] = bv;
        else if (reg == 1)
          Ko[(((size_t)b * TH + h) * TS + s) * THS + d] = bv;
        else
          VTo[(((size_t)b * TH + h) * THS + d) * TS + s] = bv;
      }
    }
  }
}

// ---------------- flash attention, causal, swapped-operand in-register softmax ----------------
// 1 block = 1 wave = 32 q-rows. KVBLK=64 (two 32x32 S-subtiles, one combined softmax pass).
// XCD-locality: lin%8 selects XCD-group; each XCD-group owns 4 (b,h) pairs -> K/V stay
// L2-resident (2 MB / 4 MB). Zigzag qt assignment balances the causal triangle per CU.
// Defer-rescale (T13): skip O-rescale when tile max doesn't exceed running max + 8/c.
__global__ __launch_bounds__(64) void k_attn(const unsigned short* __restrict__ Q,
                                             const unsigned short* __restrict__ K,
                                             const unsigned short* __restrict__ VT,
                                             unsigned short* __restrict__ attn) {
  __shared__ unsigned short sO[32 * 68];  // O transpose buffer, stride 68
  const int lane = threadIdx.x;
  const int l31 = lane & 31, h = lane >> 5;

  const int lin = blockIdx.x;
  const int xcd = lin & 7, j = lin >> 3;      // j in [0,256)
  const int g = j >> 6, jj = j & 63;
  const int qt = (jj & 1) ? (jj >> 1) : 63 - (jj >> 1);  // zigzag: 63,0,62,1,...
  const int pair = xcd * 4 + g;               // 4 (b,h) pairs per XCD
  const int b = pair >> 4, hh = pair & 15;
  const int qrb = qt * 32;

  const unsigned short* Qh = Q + (((size_t)b * TH + hh) * TS) * THS;
  const unsigned short* Kh = K + (((size_t)b * TH + hh) * TS) * THS;
  const unsigned short* Vh = VT + (((size_t)b * TH + hh) * THS) * TS;

  // Q B-frags: lane holds row (qrb + l31), d-chunk c*16 + h*8
  short8 qf[4];
#pragma unroll
  for (int c2 = 0; c2 < 4; ++c2)
    qf[c2] = *(const short8*)&Qh[(size_t)(qrb + l31) * THS + c2 * 16 + h * 8];

  f32x16 o0 = {}, o1 = {};
  float m_run = -1e30f, l_run = 0.f;
  const float cl2e = 0.125f * 1.44269504088896340736f;  // scale * log2(e)
  const float THR = 8.0f / cl2e;                        // defer-rescale threshold (raw-score)

  const int nkt = (qrb >> 6) + 1;  // 64-wide KV tiles

  // K A-frags tile 0: kf[t*4+c2] = K row (t*32+l31), d-chunk c2
  short8 kf[8];
#pragma unroll
  for (int t = 0; t < 2; ++t)
#pragma unroll
    for (int c2 = 0; c2 < 4; ++c2)
      kf[t * 4 + c2] = *(const short8*)&Kh[(size_t)(t * 32 + l31) * THS + c2 * 16 + h * 8];

  // V^T A-frags tile 0: vf[t*4+c] = V^T row d=(t*32+l31), k-chunk c (16 wide)
  short8 vf[8];
#pragma unroll
  for (int t = 0; t < 2; ++t)
#pragma unroll
    for (int c = 0; c < 4; ++c)
      vf[t * 4 + c] = *(const short8*)&Vh[(size_t)(t * 32 + l31) * TS + c * 16 + h * 8];

  for (int kt = 0; kt < nkt; ++kt) {
    const int kb = kt * 64;
    const bool last = (kt == nkt - 1);
    const bool have2 = (kb + 32) <= (qrb + 31);  // second k-subtile has any valid k

    // S^T subtiles
    f32x16 s0 = {}, s1 = {};
#pragma unroll
    for (int c2 = 0; c2 < 4; ++c2)
      s0 = __builtin_amdgcn_mfma_f32_32x32x16_bf16(kf[c2], qf[c2], s0, 0, 0, 0);
    if (have2) {
#pragma unroll
      for (int c2 = 0; c2 < 4; ++c2)
        s1 = __builtin_amdgcn_mfma_f32_32x32x16_bf16(kf[4 + c2], qf[c2], s1, 0, 0, 0);
    }

    // prefetch next K tile (in-place WAR)
    if (kt + 1 < nkt) {
#pragma unroll
      for (int t = 0; t < 2; ++t)
#pragma unroll
        for (int c2 = 0; c2 < 4; ++c2)
          kf[t * 4 + c2] = *(const short8*)&Kh[(size_t)(kb + 64 + t * 32 + l31) * THS + c2 * 16 + h * 8];
    }

    // causal mask on the diagonal subtile (k-base == qrb): k = base + km, q = qrb + l31
    if (last) {
      if (kb == qrb) {
#pragma unroll
        for (int r = 0; r < 16; ++r)
          if ((r & 3) + 4 * h + 8 * (r >> 2) > l31) s0[r] = -1e30f;
      } else {
#pragma unroll
        for (int r = 0; r < 16; ++r)
          if ((r & 3) + 4 * h + 8 * (r >> 2) > l31) s1[r] = -1e30f;
      }
    }

    // combined online softmax (per-lane q = qrb + l31, replicated across halves)
    float tm = s0[0];
#pragma unroll
    for (int r = 1; r < 16; ++r) tm = fmaxf(tm, s0[r]);
    if (have2) {
#pragma unroll
      for (int r = 0; r < 16; ++r) tm = fmaxf(tm, s1[r]);
    }
    tm = fmaxf(tm, __shfl_xor(tm, 32));

    float al;
    if (__all(tm <= m_run + THR)) {
      al = 1.0f;  // defer: keep old max, P bounded by exp2(8)
    } else {
      const float mn = fmaxf(m_run, tm);
      al = __builtin_amdgcn_exp2f((m_run - mn) * cl2e);
      m_run = mn;
      o0 *= al;
      o1 *= al;
    }
    float ts = 0.f;
#pragma unroll
    for (int r = 0; r < 16; ++r) {
      const float p = __builtin_amdgcn_exp2f((s0[r] - m_run) * cl2e);
      s0[r] = p;
      ts += p;
    }
    if (have2) {
#pragma unroll
      for (int r = 0; r < 16; ++r) {
        const float p = __builtin_amdgcn_exp2f((s1[r] - m_run) * cl2e);
        s1[r] = p;
        ts += p;
      }
    }
    ts += __shfl_xor(ts, 32);
    l_run = l_run * al + ts;

    // P^T B-frags via cvt_pk + permlane32_swap
    union U { uint4v u; short8 s8; } u0, u1, u2, u3;
    {
      unsigned B0 = cvtpk(s0[0], s0[1]), B1 = cvtpk(s0[2], s0[3]);
      unsigned B2 = cvtpk(s0[4], s0[5]), B3 = cvtpk(s0[6], s0[7]);
      swap32(B0, B2);
      swap32(B1, B3);
      unsigned B4 = cvtpk(s0[8], s0[9]), B5 = cvtpk(s0[10], s0[11]);
      unsigned B6 = cvtpk(s0[12], s0[13]), B7 = cvtpk(s0[14], s0[15]);
      swap32(B4, B6);
      swap32(B5, B7);
      u0.u = (uint4v){B0, B1, B2, B3};
      u1.u = (uint4v){B4, B5, B6, B7};
    }
    o0 = __builtin_amdgcn_mfma_f32_32x32x16_bf16(vf[0], u0.s8, o0, 0, 0, 0);
    o0 = __builtin_amdgcn_mfma_f32_32x32x16_bf16(vf[1], u1.s8, o0, 0, 0, 0);
    o1 = __builtin_amdgcn_mfma_f32_32x32x16_bf16(vf[4], u0.s8, o1, 0, 0, 0);
    o1 = __builtin_amdgcn_mfma_f32_32x32x16_bf16(vf[5], u1.s8, o1, 0, 0, 0);
    if (have2) {
      unsigned C0 = cvtpk(s1[0], s1[1]), C1 = cvtpk(s1[2], s1[3]);
      unsigned C2 = cvtpk(s1[4], s1[5]), C3 = cvtpk(s1[6], s1[7]);
      swap32(C0, C2);
      swap32(C1, C3);
      unsigned C4 = cvtpk(s1[8], s1[9]), C5 = cvtpk(s1[10], s1[11]);
      unsigned C6 = cvtpk(s1[12], s1[13]), C7 = cvtpk(s1[14], s1[15]);
      swap32(C4, C6);
      swap32(C5, C7);
      u2.u = (uint4v){C0, C1, C2, C3};
      u3.u = (uint4v){C4, C5, C6, C7};
      o0 = __builtin_amdgcn_mfma_f32_32x32x16_bf16(vf[2], u2.s8, o0, 0, 0, 0);
      o0 = __builtin_amdgcn_mfma_f32_32x32x16_bf16(vf[3], u3.s8, o0, 0, 0, 0);
      o1 = __builtin_amdgcn_mfma_f32_32x32x16_bf16(vf[6], u2.s8, o1, 0, 0, 0);
      o1 = __builtin_amdgcn_mfma_f32_32x32x16_bf16(vf[7], u3.s8, o1, 0, 0, 0);
    }

    // prefetch next V tile (in-place WAR, consumed after next tile's softmax)
    if (kt + 1 < nkt) {
#pragma unroll
      for (int t = 0; t < 2; ++t)
#pragma unroll
        for (int c = 0; c < 4; ++c)
          vf[t * 4 + c] = *(const short8*)&Vh[(size_t)(t * 32 + l31) * TS + kb + 64 + c * 16 + h * 8];
    }
  }

  // epilogue: O^T -> LDS (single wave, no barrier) -> coalesced global store
  const float inv = 1.0f / l_run;
  unsigned* so32 = (unsigned*)&sO[0];
#pragma unroll
  for (int j2 = 0; j2 < 8; ++j2) {
    const int d0 = ((2 * j2) & 3) + 8 * (j2 >> 1) + 4 * h;  // even d of the pair
    so32[l31 * 34 + (d0 >> 1)] = cvtpk(o0[2 * j2] * inv, o0[2 * j2 + 1] * inv);
    so32[l31 * 34 + ((32 + d0) >> 1)] = cvtpk(o1[2 * j2] * inv, o1[2 * j2 + 1] * inv);
  }
#pragma unroll
  for (int p2 = 0; p2 < 4; ++p2) {
    const int rp = p2 * 8 + (lane >> 3);
    const int co = (lane & 7) * 8;
    short4v va = *(const short4v*)&sO[rp * 68 + co];
    short4v vb = *(const short4v*)&sO[rp * 68 + co + 4];
    unsigned short* gp = &attn[(size_t)(b * TS + qrb + rp) * TD + hh * THS + co];
    *(short4v*)gp = va;
    *(short4v*)(gp + 4) = vb;
  }
}

// ---------------- GEMM2: out = attn @ wpT^T + bias (fp32 out) ----------------
__global__ __launch_bounds__(256) void k_gemm_proj(const unsigned short* __restrict__ A,
                                                   const unsigned short* __restrict__ BT,
                                                   const float* __restrict__ bias,
                                                   float* __restrict__ out) {
  __shared__ unsigned short sA[2 * 4096];
  __shared__ unsigned short sB[2 * 4096];
  f32x4 acc[4][4];
  const int m0 = blockIdx.y * 128, n0 = blockIdx.x * 128;
  gemm_core_k1024(A, BT, m0, n0, sA, sB, acc);

  const int lane = threadIdx.x & 63, wave = threadIdx.x >> 6;
  const int wm = wave >> 1, wn = wave & 1;
  const int lr4 = (lane >> 4) * 4, l15 = lane & 15;
#pragma unroll
  for (int mi = 0; mi < 4; ++mi) {
    const int row = m0 + wm * 64 + mi * 16 + lr4;
#pragma unroll
    for (int ni = 0; ni < 4; ++ni) {
      const int col = n0 + wn * 64 + ni * 16 + l15;
      const float bi = bias[col];
#pragma unroll
      for (int j = 0; j < 4; ++j)
        out[(size_t)(row + j) * TD + col] = acc[mi][ni][j] + bi;
    }
  }
}

extern "C" void kernel_launch(void* const* d_in, const int* in_sizes, int n_in,
                              void* d_out, int out_size, void* d_ws, size_t ws_size,
                              hipStream_t stream) {
  const float* x = (const float*)d_in[0];
  const float* c_attn_w = (const float*)d_in[1];
  const float* c_attn_b = (const float*)d_in[2];
  const float* c_proj_w = (const float*)d_in[3];
  const float* c_proj_b = (const float*)d_in[4];
  float* out = (float*)d_out;

  const size_t SZ_XB = (size_t)4096 * 1024 * 2;
  const size_t SZ_WAT = (size_t)3072 * 1024 * 2;
  const size_t SZ_WPT = (size_t)1024 * 1024 * 2;
  const size_t SZ_HEAD = (size_t)TB * TH * TS * THS * 2;
  const size_t SZ_ATT = (size_t)4096 * 1024 * 2;
  if (ws_size < SZ_XB + SZ_WAT + SZ_WPT + 3 * SZ_HEAD + SZ_ATT) return;

  char* ws = (char*)d_ws;
  unsigned short* xb = (unsigned short*)ws;   ws += SZ_XB;
  unsigned short* waT = (unsigned short*)ws;  ws += SZ_WAT;
  unsigned short* wpT = (unsigned short*)ws;  ws += SZ_WPT;
  unsigned short* Qb = (unsigned short*)ws;   ws += SZ_HEAD;
  unsigned short* Kb = (unsigned short*)ws;   ws += SZ_HEAD;
  unsigned short* VTb = (unsigned short*)ws;  ws += SZ_HEAD;
  unsigned short* attn = (unsigned short*)ws; ws += SZ_ATT;

  k_cvt_bf16x4<<<4096, 256, 0, stream>>>(x, (ushort4*)xb, 4096 * 1024 / 4);
  k_transpose_bf<<<dim3(3072 / 32, 1024 / 32), 256, 0, stream>>>(c_attn_w, waT, 1024, 3072);
  k_transpose_bf<<<dim3(1024 / 32, 1024 / 32), 256, 0, stream>>>(c_proj_w, wpT, 1024, 1024);
  k_gemm_qkv<<<dim3(3072 / 128, 4096 / 128), 256, 0, stream>>>(xb, waT, c_attn_b, Qb, Kb, VTb);
  k_attn<<<dim3(2048), 64, 0, stream>>>(Qb, Kb, VTb, attn);
  k_gemm_proj<<<dim3(1024 / 128, 4096 / 128), 256, 0, stream>>>(attn, wpT, c_proj_b, out);
}